// Round 7
// baseline (302.946 us; speedup 1.0000x reference)
//
#include <hip/hip_runtime.h>
#include <stdint.h>

#define B_ROWS 4096
#define N_ROWS 8192
#define D_DIM  1024                     // elements per row (= bytes in fp8)
#define BKB    128                      // k-bytes staged per iter
#define NBI    64                       // 8192 / 128 row-tiles
#define NBJ    128                      // 8192 / 64  col-tiles
#define NT     4160                     // tiles with bj >= 2*bi
typedef __attribute__((ext_vector_type(2))) long longx2;
typedef __attribute__((ext_vector_type(4))) float f32x4;

static __device__ __forceinline__ void async_copy16(const unsigned char* g, unsigned char* l) {
  __builtin_amdgcn_global_load_lds(
      (const __attribute__((address_space(1))) unsigned int*)g,
      (__attribute__((address_space(3))) unsigned int*)l, 16, 0, 0);
}

// One wave per row: L2-normalize, cast to fp8 e4m3, zero rowsum (+ctr).
__global__ __launch_bounds__(256) void normalize_kernel(
    const float* __restrict__ f1, const float* __restrict__ f2,
    unsigned char* __restrict__ F, float* __restrict__ rowsum,
    unsigned int* __restrict__ ctr) {
  const int wv   = threadIdx.x >> 6;
  const int lane = threadIdx.x & 63;
  const int row  = blockIdx.x * 4 + wv;
  const float* src = (row < B_ROWS) ? (f1 + (size_t)row * D_DIM)
                                    : (f2 + (size_t)(row - B_ROWS) * D_DIM);
  const float4* s4 = (const float4*)src;
  float4 v[4];
  float ss = 0.0f;
#pragma unroll
  for (int r = 0; r < 4; ++r) {
    v[r] = s4[lane * 4 + r];
    ss += v[r].x * v[r].x + v[r].y * v[r].y + v[r].z * v[r].z + v[r].w * v[r].w;
  }
#pragma unroll
  for (int m = 1; m < 64; m <<= 1) ss += __shfl_xor(ss, m, 64);
  const float invn = 1.0f / fmaxf(sqrtf(ss), 1e-12f);
  uint32_t p[4];
#pragma unroll
  for (int r = 0; r < 4; ++r) {
    uint32_t lo = __builtin_amdgcn_cvt_pk_fp8_f32(v[r].x * invn, v[r].y * invn, 0, false);
    p[r] = __builtin_amdgcn_cvt_pk_fp8_f32(v[r].z * invn, v[r].w * invn, lo, true);
  }
  uint4 o; o.x = p[0]; o.y = p[1]; o.z = p[2]; o.w = p[3];
  ((uint4*)(F + (size_t)row * D_DIM))[lane] = o;
  if (lane == 0) rowsum[row] = 0.0f;
  if (row == 0 && lane == 0) *ctr = 0u;
}

// Fused Gram-GEMM (fp8) + exp-sum + fused finalize.
// ASYMMETRIC 128x64 tiles (A=128 rows, B=64 cols), tiles kept iff
// bj*64 >= bi*128 (j-tile at-or-right-of diagonal). Uniform j>i predicate:
// every counted element is strictly upper-triangular and contributes
// exp(sim-10) to BOTH rowsum[i] (row-reduce) and rowsum[j] (col-reduce).
// 4 waves; each wave 64x32 -> acc = 4x2 f32x4 = 32 AGPR (HALF of R6) so
// ~5 blocks/CU become resident to overlap the per-iter vmcnt(0) drain.
// Zero-conflict LDS addressing (R2-verified): chunk (r,c) stored at
// r*8 + (c ^ (r&7)); lane reads chunk pair c = q and c = q^4.
__global__ __launch_bounds__(256) void simloss_kernel(
    const unsigned char* __restrict__ F, float* __restrict__ rowsum,
    float* __restrict__ pos, unsigned int* __restrict__ ctr,
    float* __restrict__ out) {
  __shared__ unsigned char lA[128 * BKB];   // 16 KB
  __shared__ unsigned char lB[64 * BKB];    // 8 KB

  // XCD band swizzle: 4160 = 8 * 520.
  const int b    = (int)blockIdx.x;
  const int tile = (b & 7) * (NT / 8) + (b >> 3);

  // decode tile -> (bi, bj): bi has (NBJ - 2*bi) kept tiles; bj = 2*bi + rem
  int rem = tile;
  int bi = 0;
  while (rem >= NBJ - 2 * bi) { rem -= NBJ - 2 * bi; ++bi; }
  const int bj = 2 * bi + rem;

  const int tid  = threadIdx.x;
  const int lane = tid & 63;
  const int wv   = __builtin_amdgcn_readfirstlane(tid >> 6);
  const int waveRow = wv >> 1;   // 0..1 -> 64-row half of A
  const int waveCol = wv & 1;    // 0..1 -> 32-col half of B
  const int q   = lane >> 4;
  const int l16 = lane & 15;

  const int iBase = bi * 128;
  const int jBase = bj * 64;
  const unsigned char* Abase = F + (size_t)iBase * D_DIM;
  const unsigned char* Bbase = F + (size_t)jBase * D_DIM;

  f32x4 acc[4][2];
#pragma unroll
  for (int a = 0; a < 4; ++a)
#pragma unroll
    for (int c = 0; c < 2; ++c) acc[a][c] = (f32x4){0.f, 0.f, 0.f, 0.f};

  // staging chunk ids: A = 1024 chunks (4/thread), B = 512 chunks (2/thread)
  int sA_lc[4], sA_go[4], sB_lc[2], sB_go[2];
#pragma unroll
  for (int c4 = 0; c4 < 4; ++c4) {
    const int lc = c4 * 256 + tid;
    const int r  = lc >> 3;
    sA_lc[c4] = lc;
    sA_go[c4] = r * D_DIM + ((lc & 7) ^ (r & 7)) * 16;
  }
#pragma unroll
  for (int c2 = 0; c2 < 2; ++c2) {
    const int lc = c2 * 256 + tid;
    const int r  = lc >> 3;
    sB_lc[c2] = lc;
    sB_go[c2] = r * D_DIM + ((lc & 7) ^ (r & 7)) * 16;
  }
  // reader byte addresses (iteration-invariant): pair c=q, c=q^4
  int rdA[4][2], rdB[2][2];
#pragma unroll
  for (int mi = 0; mi < 4; ++mi) {
    const int r = waveRow * 64 + mi * 16 + l16;
    rdA[mi][0] = (r * 8 + (q ^ (r & 7))) * 16;
    rdA[mi][1] = (r * 8 + ((q ^ 4) ^ (r & 7))) * 16;
  }
#pragma unroll
  for (int ni = 0; ni < 2; ++ni) {
    const int r = waveCol * 32 + ni * 16 + l16;
    rdB[ni][0] = (r * 8 + (q ^ (r & 7))) * 16;
    rdB[ni][1] = (r * 8 + ((q ^ 4) ^ (r & 7))) * 16;
  }

  for (int k0 = 0; k0 < D_DIM; k0 += BKB) {
#pragma unroll
    for (int c4 = 0; c4 < 4; ++c4)
      async_copy16(Abase + k0 + sA_go[c4], &lA[sA_lc[c4] * 16]);
#pragma unroll
    for (int c2 = 0; c2 < 2; ++c2)
      async_copy16(Bbase + k0 + sB_go[c2], &lB[sB_lc[c2] * 16]);
    __syncthreads();

    longx2 a0[4], a1[4], b0[2], b1[2];
#pragma unroll
    for (int mi = 0; mi < 4; ++mi) {
      a0[mi] = *(const longx2*)&lA[rdA[mi][0]];   // k-substeps 0,1 (@ c=q)
      a1[mi] = *(const longx2*)&lA[rdA[mi][1]];   // k-substeps 2,3 (@ c=q^4)
    }
#pragma unroll
    for (int ni = 0; ni < 2; ++ni) {
      b0[ni] = *(const longx2*)&lB[rdB[ni][0]];
      b1[ni] = *(const longx2*)&lB[rdB[ni][1]];
    }
#pragma unroll
    for (int mi = 0; mi < 4; ++mi)
#pragma unroll
      for (int ni = 0; ni < 2; ++ni)
        acc[mi][ni] = __builtin_amdgcn_mfma_f32_16x16x32_fp8_fp8(
            a0[mi].x, b0[ni].x, acc[mi][ni], 0, 0, 0);
#pragma unroll
    for (int mi = 0; mi < 4; ++mi)
#pragma unroll
      for (int ni = 0; ni < 2; ++ni)
        acc[mi][ni] = __builtin_amdgcn_mfma_f32_16x16x32_fp8_fp8(
            a0[mi].y, b0[ni].y, acc[mi][ni], 0, 0, 0);
#pragma unroll
    for (int mi = 0; mi < 4; ++mi)
#pragma unroll
      for (int ni = 0; ni < 2; ++ni)
        acc[mi][ni] = __builtin_amdgcn_mfma_f32_16x16x32_fp8_fp8(
            a1[mi].x, b1[ni].x, acc[mi][ni], 0, 0, 0);
#pragma unroll
    for (int mi = 0; mi < 4; ++mi)
#pragma unroll
      for (int ni = 0; ni < 2; ++ni)
        acc[mi][ni] = __builtin_amdgcn_mfma_f32_16x16x32_fp8_fp8(
            a1[mi].y, b1[ni].y, acc[mi][ni], 0, 0, 0);
    __syncthreads();
  }

  // ---- epilogue: strictly-upper elements only (j > i); each contributes
  // to rowsum[i] and rowsum[j]. sim = 10*dot.
  float colAcc[2] = {0.f, 0.f};
#pragma unroll
  for (int mi = 0; mi < 4; ++mi) {
#pragma unroll
    for (int reg = 0; reg < 4; ++reg) {
      const int i = iBase + waveRow * 64 + mi * 16 + q * 4 + reg;
      float s = 0.0f;
#pragma unroll
      for (int ni = 0; ni < 2; ++ni) {
        const int j = jBase + waveCol * 32 + ni * 16 + l16;
        const float sim = acc[mi][ni][reg] * 10.0f;
        const float e = (j > i) ? __expf(sim - 10.0f) : 0.0f;
        s += e;
        colAcc[ni] += e;
        if (j == i + B_ROWS) pos[i] = sim;
      }
#pragma unroll
      for (int m = 1; m < 16; m <<= 1) s += __shfl_xor(s, m, 64);
      if (l16 == 0) atomicAdd(&rowsum[i], s);
    }
  }
#pragma unroll
  for (int ni = 0; ni < 2; ++ni) {
    float c = colAcc[ni];
#pragma unroll
    for (int m = 16; m < 64; m <<= 1) c += __shfl_xor(c, m, 64);
    if (q == 0) {
      const int j = jBase + waveCol * 32 + ni * 16 + l16;
      atomicAdd(&rowsum[j], c);
    }
  }

  // ---- fused finalize: last block computes the loss ----
  __syncthreads();
  __shared__ unsigned int lastFlag;
  if (tid == 0) {
    __threadfence();
    const unsigned int old = atomicAdd(ctr, 1u);
    lastFlag = (old == (unsigned int)(NT - 1)) ? 1u : 0u;
  }
  __syncthreads();
  if (lastFlag) {
    __threadfence();
    float a = 0.0f;
    for (int i = tid; i < N_ROWS; i += 256)
      a += __logf(rowsum[i]) + 10.0f - pos[i & (B_ROWS - 1)];
#pragma unroll
    for (int m = 1; m < 64; m <<= 1) a += __shfl_xor(a, m, 64);
    __shared__ float red[4];
    if ((tid & 63) == 0) red[tid >> 6] = a;
    __syncthreads();
    if (tid == 0) out[0] = (red[0] + red[1] + red[2] + red[3]) * (1.0f / N_ROWS);
  }
}

extern "C" void kernel_launch(void* const* d_in, const int* in_sizes, int n_in,
                              void* d_out, int out_size, void* d_ws, size_t ws_size,
                              hipStream_t stream) {
  const float* f1 = (const float*)d_in[0];
  const float* f2 = (const float*)d_in[1];
  unsigned char* F = (unsigned char*)d_ws;                        // 8 MiB fp8 features
  float* rowsum = (float*)((char*)d_ws + (size_t)N_ROWS * D_DIM); // 32 KiB
  float* pos    = rowsum + N_ROWS;                                // 16 KiB (i < B_ROWS)
  unsigned int* ctr = (unsigned int*)(pos + B_ROWS);              // 4 B
  float* out    = (float*)d_out;

  hipLaunchKernelGGL(normalize_kernel, dim3(N_ROWS / 4), dim3(256), 0, stream,
                     f1, f2, F, rowsum, ctr);
  hipLaunchKernelGGL(simloss_kernel, dim3(NT), dim3(256), 0, stream,
                     F, rowsum, pos, ctr, out);
}